// Round 19
// baseline (31.082 us; speedup 1.0000x reference)
//
#include <hip/hip_runtime.h>

#define BB 4
#define CC 512    // C_CTX
#define TDIM 512  // T
#define HH 128
#define TT 8      // t-rows per block

// ---------------- prep: key/query/value projections (f32 to ws) -------------
__global__ __launch_bounds__(128) void prep_kernel(
    const float* __restrict__ ctx_x, const float* __restrict__ ctx_y,
    const float* __restrict__ tgt_x,
    const float* __restrict__ W_in, const float* __restrict__ b_in,
    const float* __restrict__ W_ctx, const float* __restrict__ b_ctx,
    float* __restrict__ key, float* __restrict__ query, float* __restrict__ value)
{
    int row = blockIdx.x;     // b*512 + r
    int h   = threadIdx.x;    // 0..127

    float4 cx = ((const float4*)ctx_x)[row];
    float2 cy = ((const float2*)ctx_y)[row];
    float4 tx = ((const float4*)tgt_x)[row];

    float wi0 = W_in[0*HH+h], wi1 = W_in[1*HH+h], wi2 = W_in[2*HH+h];
    float wi3 = W_in[3*HH+h], wi4 = W_in[4*HH+h];
    float wc0 = W_ctx[0*HH+h], wc1 = W_ctx[1*HH+h], wc2 = W_ctx[2*HH+h];
    float bi  = b_in[h], bc = b_ctx[h];

    value[row*HH+h] = fmaf(cx.x,wi0, fmaf(cx.y,wi1, fmaf(cx.z,wi2, fmaf(cy.x,wi3, fmaf(cy.y,wi4, bi)))));
    key  [row*HH+h] = fmaf(cx.x,wc0, fmaf(cx.y,wc1, fmaf(cx.z,wc2, bc)));
    query[row*HH+h] = fmaf(tx.x,wc0, fmaf(tx.y,wc1, fmaf(tx.z,wc2, bc)));
}

// ---------- fused (R12 structure + in-register software pipelining).
// 256 blocks x 512 thr; 8 waves = 4 c-ranges(128) x 2 t-halves(4 rows).
// Each wave: pipelined score -> single-pass softmax -> pipelined PV.
// 2 barriers total; in-block flash-merge + projection.
__global__ __launch_bounds__(512) void fused_kernel(
    const float* __restrict__ key, const float* __restrict__ query,
    const float* __restrict__ value, const float* __restrict__ W_tgt,
    const float* __restrict__ b_tgt, float* __restrict__ out)
{
    const int bx   = blockIdx.x;          // b*64 + tb
    const int b    = bx >> 6;
    const int t0   = (bx & 63) * TT;
    const int tid  = threadIdx.x;         // 0..511
    const int wave = tid >> 6;            // 0..7
    const int cr   = wave & 3;            // c-range [cr*128, +128)
    const int th   = wave >> 2;           // t-half: rows th*4 .. +3
    const int lane = tid & 63;

    __shared__ __align__(16) float s_w[8][4][128];     // 16 KB wave-private scores
    __shared__ __align__(16) float pT_w[8][128][4];    // 16 KB wave-private exp^T
    __shared__ __align__(16) float2 wml[8][4];         // (m,l) per wave per t-local
    __shared__ __align__(16) float partial[8][4][HH];  // 16 KB wave PV partials
    __shared__ __align__(16) float rep[TT][HH];        // 4 KB

    // --- score role: (cl = c-quad 0..7, hq = h-oct 0..7); q in 64 VGPR ---
    const int cl = lane >> 3;
    const int hq = lane & 7;
    float4 qr[4][4];
    #pragma unroll
    for (int tt = 0; tt < 4; ++tt)
        #pragma unroll
        for (int j = 0; j < 4; ++j)
            qr[tt][j] = *(const float4*)&query[(b*TDIM + t0 + th*4 + tt)*HH + j*32 + hq*4];

    // ---- SCORE: 16 fully-unrolled steps (pass = s>>2 picks 32-row group,
    //      j = s&3 picks h-chunk), 1-step register prefetch kn -> kc. ----
    {
        const float* kbase = &key[(b*CC + cr*128 + cl*4)*HH + hq*4];
        float4 kn0 = *(const float4*)(kbase + 0*HH);
        float4 kn1 = *(const float4*)(kbase + 1*HH);
        float4 kn2 = *(const float4*)(kbase + 2*HH);
        float4 kn3 = *(const float4*)(kbase + 3*HH);
        float acc0[4], acc1[4], acc2[4], acc3[4];
        #pragma unroll
        for (int s = 0; s < 16; ++s) {
            const int pass = s >> 2, j = s & 3;
            float4 kc0 = kn0, kc1 = kn1, kc2 = kn2, kc3 = kn3;
            if (s < 15) {
                const int sn = s + 1;
                const float* np = kbase + (sn>>2)*32*HH + (sn&3)*32;
                kn0 = *(const float4*)(np + 0*HH);
                kn1 = *(const float4*)(np + 1*HH);
                kn2 = *(const float4*)(np + 2*HH);
                kn3 = *(const float4*)(np + 3*HH);
            }
            if (j == 0) {
                #pragma unroll
                for (int tt = 0; tt < 4; ++tt) { acc0[tt]=0.f; acc1[tt]=0.f; acc2[tt]=0.f; acc3[tt]=0.f; }
            }
            #pragma unroll
            for (int tt = 0; tt < 4; ++tt) {
                float4 qv = qr[tt][j];
                acc0[tt] += fabsf(kc0.x-qv.x)+fabsf(kc0.y-qv.y)+fabsf(kc0.z-qv.z)+fabsf(kc0.w-qv.w);
                acc1[tt] += fabsf(kc1.x-qv.x)+fabsf(kc1.y-qv.y)+fabsf(kc1.z-qv.z)+fabsf(kc1.w-qv.w);
                acc2[tt] += fabsf(kc2.x-qv.x)+fabsf(kc2.y-qv.y)+fabsf(kc2.z-qv.z)+fabsf(kc2.w-qv.w);
                acc3[tt] += fabsf(kc3.x-qv.x)+fabsf(kc3.y-qv.y)+fabsf(kc3.z-qv.z)+fabsf(kc3.w-qv.w);
            }
            if (j == 3) {
                #pragma unroll
                for (int tt = 0; tt < 4; ++tt) {
                    float v0=acc0[tt], v1=acc1[tt], v2=acc2[tt], v3=acc3[tt];
                    v0 += __shfl_xor(v0,1); v0 += __shfl_xor(v0,2); v0 += __shfl_xor(v0,4);
                    v1 += __shfl_xor(v1,1); v1 += __shfl_xor(v1,2); v1 += __shfl_xor(v1,4);
                    v2 += __shfl_xor(v2,1); v2 += __shfl_xor(v2,2); v2 += __shfl_xor(v2,4);
                    v3 += __shfl_xor(v3,1); v3 += __shfl_xor(v3,2); v3 += __shfl_xor(v3,4);
                    if (hq == 0)
                        *(float4*)&s_w[wave][tt][pass*32 + cl*4] =
                            make_float4(-0.5f*v0, -0.5f*v1, -0.5f*v2, -0.5f*v3);
                }
            }
        }
    }
    // same-wave LDS handoff: no barrier

    // ---- single-pass softmax (16-lane group tg owns t-local tg, 128 c) ----
    {
        const int tg = lane >> 4, ci = lane & 15;
        float4 x0 = *(const float4*)&s_w[wave][tg][ci*8];
        float4 x1 = *(const float4*)&s_w[wave][tg][ci*8 + 4];
        float m = fmaxf(fmaxf(fmaxf(x0.x,x0.y), fmaxf(x0.z,x0.w)),
                        fmaxf(fmaxf(x1.x,x1.y), fmaxf(x1.z,x1.w)));
        m = fmaxf(m, __shfl_xor(m,1)); m = fmaxf(m, __shfl_xor(m,2));
        m = fmaxf(m, __shfl_xor(m,4)); m = fmaxf(m, __shfl_xor(m,8));
        float e0 = __expf(x0.x-m), e1 = __expf(x0.y-m), e2 = __expf(x0.z-m), e3 = __expf(x0.w-m);
        float e4 = __expf(x1.x-m), e5 = __expf(x1.y-m), e6 = __expf(x1.z-m), e7 = __expf(x1.w-m);
        float sm = ((e0+e1)+(e2+e3)) + ((e4+e5)+(e6+e7));
        sm += __shfl_xor(sm,1); sm += __shfl_xor(sm,2);
        sm += __shfl_xor(sm,4); sm += __shfl_xor(sm,8);
        pT_w[wave][ci*8+0][tg] = e0;  pT_w[wave][ci*8+1][tg] = e1;
        pT_w[wave][ci*8+2][tg] = e2;  pT_w[wave][ci*8+3][tg] = e3;
        pT_w[wave][ci*8+4][tg] = e4;  pT_w[wave][ci*8+5][tg] = e5;
        pT_w[wave][ci*8+6][tg] = e6;  pT_w[wave][ci*8+7][tg] = e7;
        if (ci == 0) wml[wave][tg] = make_float2(m, sm);
    }
    // same-wave LDS handoff: no barrier

    // ---- PV over own 128 rows, 1-row register prefetch vn -> vc ----
    {
        const int cs = lane >> 5, hv = lane & 31;
        float4 acc[4];
        #pragma unroll
        for (int tt = 0; tt < 4; ++tt) acc[tt] = make_float4(0.f,0.f,0.f,0.f);
        const float* vp = &value[(b*CC + cr*128 + cs*64)*HH + hv*4];
        float4 vn = *(const float4*)(vp);
        #pragma unroll
        for (int i = 0; i < 64; ++i) {
            float4 vc = vn;
            if (i < 63) vn = *(const float4*)(vp + (i+1)*HH);
            float4 p4 = *(const float4*)&pT_w[wave][cs*64 + i][0];  // 2-addr broadcast
            acc[0].x=fmaf(p4.x,vc.x,acc[0].x); acc[0].y=fmaf(p4.x,vc.y,acc[0].y);
            acc[0].z=fmaf(p4.x,vc.z,acc[0].z); acc[0].w=fmaf(p4.x,vc.w,acc[0].w);
            acc[1].x=fmaf(p4.y,vc.x,acc[1].x); acc[1].y=fmaf(p4.y,vc.y,acc[1].y);
            acc[1].z=fmaf(p4.y,vc.z,acc[1].z); acc[1].w=fmaf(p4.y,vc.w,acc[1].w);
            acc[2].x=fmaf(p4.z,vc.x,acc[2].x); acc[2].y=fmaf(p4.z,vc.y,acc[2].y);
            acc[2].z=fmaf(p4.z,vc.z,acc[2].z); acc[2].w=fmaf(p4.z,vc.w,acc[2].w);
            acc[3].x=fmaf(p4.w,vc.x,acc[3].x); acc[3].y=fmaf(p4.w,vc.y,acc[3].y);
            acc[3].z=fmaf(p4.w,vc.z,acc[3].z); acc[3].w=fmaf(p4.w,vc.w,acc[3].w);
        }
        #pragma unroll
        for (int tt = 0; tt < 4; ++tt) {
            acc[tt].x += __shfl_xor(acc[tt].x, 32);
            acc[tt].y += __shfl_xor(acc[tt].y, 32);
            acc[tt].z += __shfl_xor(acc[tt].z, 32);
            acc[tt].w += __shfl_xor(acc[tt].w, 32);
        }
        if (cs == 0) {
            #pragma unroll
            for (int tt = 0; tt < 4; ++tt)
                *(float4*)&partial[wave][tt][hv*4] = acc[tt];
        }
    }
    __syncthreads();

    // ---- flash-merge 4 c-ranges per t-half -> rep ----
    #pragma unroll
    for (int e = tid; e < TT*HH; e += 512) {
        const int t = e >> 7, h = e & 127;
        const int thh = t >> 2, tl = t & 3;
        float2 q0 = wml[thh*4+0][tl], q1 = wml[thh*4+1][tl];
        float2 q2 = wml[thh*4+2][tl], q3 = wml[thh*4+3][tl];
        float M = fmaxf(fmaxf(q0.x,q1.x), fmaxf(q2.x,q3.x));
        float a0 = __expf(q0.x-M), a1 = __expf(q1.x-M);
        float a2 = __expf(q2.x-M), a3 = __expf(q3.x-M);
        float L = fmaf(a0,q0.y, fmaf(a1,q1.y, fmaf(a2,q2.y, a3*q3.y)));
        float r = a0*partial[thh*4+0][tl][h] + a1*partial[thh*4+1][tl][h]
                + a2*partial[thh*4+2][tl][h] + a3*partial[thh*4+3][tl][h];
        rep[t][h] = r / L;
    }
    __syncthreads();

    // ---- projection: thread (lt 0..3, h) -> rows lt and lt+4 ----
    {
        const int lt = tid >> 7, h = tid & 127;
        float o0 = b_tgt[h], o1 = o0;
        for (int k = 0; k < HH; k += 4) {
            float4 r0 = *(const float4*)&rep[lt    ][k];
            float4 r1 = *(const float4*)&rep[lt + 4][k];
            float w0 = W_tgt[(k+0)*HH + h];
            float w1 = W_tgt[(k+1)*HH + h];
            float w2 = W_tgt[(k+2)*HH + h];
            float w3 = W_tgt[(k+3)*HH + h];
            o0 = fmaf(r0.x,w0, fmaf(r0.y,w1, fmaf(r0.z,w2, fmaf(r0.w,w3, o0))));
            o1 = fmaf(r1.x,w0, fmaf(r1.y,w1, fmaf(r1.z,w2, fmaf(r1.w,w3, o1))));
        }
        out[(b*TDIM + t0 + lt    )*HH + h] = o0;
        out[(b*TDIM + t0 + lt + 4)*HH + h] = o1;
    }
}

extern "C" void kernel_launch(void* const* d_in, const int* in_sizes, int n_in,
                              void* d_out, int out_size, void* d_ws, size_t ws_size,
                              hipStream_t stream) {
    const float* ctx_x = (const float*)d_in[0];
    const float* ctx_y = (const float*)d_in[1];
    const float* tgt_x = (const float*)d_in[2];
    const float* W_in  = (const float*)d_in[3];
    const float* b_in  = (const float*)d_in[4];
    const float* W_ctx = (const float*)d_in[5];
    const float* b_ctx = (const float*)d_in[6];
    const float* W_tgt = (const float*)d_in[7];
    const float* b_tgt = (const float*)d_in[8];

    float* ws    = (float*)d_ws;
    float* key   = ws;                      // 262144 f32
    float* query = ws + 1*BB*CC*HH;         // 262144
    float* value = ws + 2*BB*CC*HH;         // 262144

    prep_kernel<<<BB*CC, 128, 0, stream>>>(ctx_x, ctx_y, tgt_x,
                                           W_in, b_in, W_ctx, b_ctx,
                                           key, query, value);
    fused_kernel<<<BB*(TDIM/TT), 512, 0, stream>>>(key, query, value,
                                                   W_tgt, b_tgt, (float*)d_out);
}

// Round 20
// 31.012 us; speedup vs baseline: 1.0023x; 1.0023x over previous
//
#include <hip/hip_runtime.h>

#define BB 4
#define CC 512    // C_CTX
#define TDIM 512  // T
#define HH 128
#define TT 8      // t-rows per block

// ---------------- prep: key/query/value projections (f32 to ws) -------------
__global__ __launch_bounds__(128) void prep_kernel(
    const float* __restrict__ ctx_x, const float* __restrict__ ctx_y,
    const float* __restrict__ tgt_x,
    const float* __restrict__ W_in, const float* __restrict__ b_in,
    const float* __restrict__ W_ctx, const float* __restrict__ b_ctx,
    float* __restrict__ key, float* __restrict__ query, float* __restrict__ value)
{
    int row = blockIdx.x;     // b*512 + r
    int h   = threadIdx.x;    // 0..127

    float4 cx = ((const float4*)ctx_x)[row];
    float2 cy = ((const float2*)ctx_y)[row];
    float4 tx = ((const float4*)tgt_x)[row];

    float wi0 = W_in[0*HH+h], wi1 = W_in[1*HH+h], wi2 = W_in[2*HH+h];
    float wi3 = W_in[3*HH+h], wi4 = W_in[4*HH+h];
    float wc0 = W_ctx[0*HH+h], wc1 = W_ctx[1*HH+h], wc2 = W_ctx[2*HH+h];
    float bi  = b_in[h], bc = b_ctx[h];

    value[row*HH+h] = fmaf(cx.x,wi0, fmaf(cx.y,wi1, fmaf(cx.z,wi2, fmaf(cy.x,wi3, fmaf(cy.y,wi4, bi)))));
    key  [row*HH+h] = fmaf(cx.x,wc0, fmaf(cx.y,wc1, fmaf(cx.z,wc2, bc)));
    query[row*HH+h] = fmaf(tx.x,wc0, fmaf(tx.y,wc1, fmaf(tx.z,wc2, bc)));
}

// ---------- fused (R12 structure + in-register software pipelining).
// 256 blocks x 512 thr; 8 waves = 4 c-ranges(128) x 2 t-halves(4 rows).
// Each wave: pipelined score -> single-pass softmax -> pipelined PV.
// 2 barriers total; in-block flash-merge + projection.
__global__ __launch_bounds__(512) void fused_kernel(
    const float* __restrict__ key, const float* __restrict__ query,
    const float* __restrict__ value, const float* __restrict__ W_tgt,
    const float* __restrict__ b_tgt, float* __restrict__ out)
{
    const int bx   = blockIdx.x;          // b*64 + tb
    const int b    = bx >> 6;
    const int t0   = (bx & 63) * TT;
    const int tid  = threadIdx.x;         // 0..511
    const int wave = tid >> 6;            // 0..7
    const int cr   = wave & 3;            // c-range [cr*128, +128)
    const int th   = wave >> 2;           // t-half: rows th*4 .. +3
    const int lane = tid & 63;

    __shared__ __align__(16) float s_w[8][4][128];     // 16 KB wave-private scores
    __shared__ __align__(16) float pT_w[8][128][4];    // 16 KB wave-private exp^T
    __shared__ __align__(16) float2 wml[8][4];         // (m,l) per wave per t-local
    __shared__ __align__(16) float partial[8][4][HH];  // 16 KB wave PV partials
    __shared__ __align__(16) float rep[TT][HH];        // 4 KB

    // --- score role: (cl = c-quad 0..7, hq = h-oct 0..7); q in 64 VGPR ---
    const int cl = lane >> 3;
    const int hq = lane & 7;
    float4 qr[4][4];
    #pragma unroll
    for (int tt = 0; tt < 4; ++tt)
        #pragma unroll
        for (int j = 0; j < 4; ++j)
            qr[tt][j] = *(const float4*)&query[(b*TDIM + t0 + th*4 + tt)*HH + j*32 + hq*4];

    // ---- SCORE: 16 fully-unrolled steps (pass = s>>2 picks 32-row group,
    //      j = s&3 picks h-chunk), 1-step register prefetch kn -> kc. ----
    {
        const float* kbase = &key[(b*CC + cr*128 + cl*4)*HH + hq*4];
        float4 kn0 = *(const float4*)(kbase + 0*HH);
        float4 kn1 = *(const float4*)(kbase + 1*HH);
        float4 kn2 = *(const float4*)(kbase + 2*HH);
        float4 kn3 = *(const float4*)(kbase + 3*HH);
        float acc0[4], acc1[4], acc2[4], acc3[4];
        #pragma unroll
        for (int s = 0; s < 16; ++s) {
            const int pass = s >> 2, j = s & 3;
            float4 kc0 = kn0, kc1 = kn1, kc2 = kn2, kc3 = kn3;
            if (s < 15) {
                const int sn = s + 1;
                const float* np = kbase + (sn>>2)*32*HH + (sn&3)*32;
                kn0 = *(const float4*)(np + 0*HH);
                kn1 = *(const float4*)(np + 1*HH);
                kn2 = *(const float4*)(np + 2*HH);
                kn3 = *(const float4*)(np + 3*HH);
            }
            if (j == 0) {
                #pragma unroll
                for (int tt = 0; tt < 4; ++tt) { acc0[tt]=0.f; acc1[tt]=0.f; acc2[tt]=0.f; acc3[tt]=0.f; }
            }
            #pragma unroll
            for (int tt = 0; tt < 4; ++tt) {
                float4 qv = qr[tt][j];
                acc0[tt] += fabsf(kc0.x-qv.x)+fabsf(kc0.y-qv.y)+fabsf(kc0.z-qv.z)+fabsf(kc0.w-qv.w);
                acc1[tt] += fabsf(kc1.x-qv.x)+fabsf(kc1.y-qv.y)+fabsf(kc1.z-qv.z)+fabsf(kc1.w-qv.w);
                acc2[tt] += fabsf(kc2.x-qv.x)+fabsf(kc2.y-qv.y)+fabsf(kc2.z-qv.z)+fabsf(kc2.w-qv.w);
                acc3[tt] += fabsf(kc3.x-qv.x)+fabsf(kc3.y-qv.y)+fabsf(kc3.z-qv.z)+fabsf(kc3.w-qv.w);
            }
            if (j == 3) {
                #pragma unroll
                for (int tt = 0; tt < 4; ++tt) {
                    float v0=acc0[tt], v1=acc1[tt], v2=acc2[tt], v3=acc3[tt];
                    v0 += __shfl_xor(v0,1); v0 += __shfl_xor(v0,2); v0 += __shfl_xor(v0,4);
                    v1 += __shfl_xor(v1,1); v1 += __shfl_xor(v1,2); v1 += __shfl_xor(v1,4);
                    v2 += __shfl_xor(v2,1); v2 += __shfl_xor(v2,2); v2 += __shfl_xor(v2,4);
                    v3 += __shfl_xor(v3,1); v3 += __shfl_xor(v3,2); v3 += __shfl_xor(v3,4);
                    if (hq == 0)
                        *(float4*)&s_w[wave][tt][pass*32 + cl*4] =
                            make_float4(-0.5f*v0, -0.5f*v1, -0.5f*v2, -0.5f*v3);
                }
            }
        }
    }
    // same-wave LDS handoff: no barrier

    // ---- single-pass softmax (16-lane group tg owns t-local tg, 128 c) ----
    {
        const int tg = lane >> 4, ci = lane & 15;
        float4 x0 = *(const float4*)&s_w[wave][tg][ci*8];
        float4 x1 = *(const float4*)&s_w[wave][tg][ci*8 + 4];
        float m = fmaxf(fmaxf(fmaxf(x0.x,x0.y), fmaxf(x0.z,x0.w)),
                        fmaxf(fmaxf(x1.x,x1.y), fmaxf(x1.z,x1.w)));
        m = fmaxf(m, __shfl_xor(m,1)); m = fmaxf(m, __shfl_xor(m,2));
        m = fmaxf(m, __shfl_xor(m,4)); m = fmaxf(m, __shfl_xor(m,8));
        float e0 = __expf(x0.x-m), e1 = __expf(x0.y-m), e2 = __expf(x0.z-m), e3 = __expf(x0.w-m);
        float e4 = __expf(x1.x-m), e5 = __expf(x1.y-m), e6 = __expf(x1.z-m), e7 = __expf(x1.w-m);
        float sm = ((e0+e1)+(e2+e3)) + ((e4+e5)+(e6+e7));
        sm += __shfl_xor(sm,1); sm += __shfl_xor(sm,2);
        sm += __shfl_xor(sm,4); sm += __shfl_xor(sm,8);
        pT_w[wave][ci*8+0][tg] = e0;  pT_w[wave][ci*8+1][tg] = e1;
        pT_w[wave][ci*8+2][tg] = e2;  pT_w[wave][ci*8+3][tg] = e3;
        pT_w[wave][ci*8+4][tg] = e4;  pT_w[wave][ci*8+5][tg] = e5;
        pT_w[wave][ci*8+6][tg] = e6;  pT_w[wave][ci*8+7][tg] = e7;
        if (ci == 0) wml[wave][tg] = make_float2(m, sm);
    }
    // same-wave LDS handoff: no barrier

    // ---- PV over own 128 rows, 1-row register prefetch vn -> vc ----
    {
        const int cs = lane >> 5, hv = lane & 31;
        float4 acc[4];
        #pragma unroll
        for (int tt = 0; tt < 4; ++tt) acc[tt] = make_float4(0.f,0.f,0.f,0.f);
        const float* vp = &value[(b*CC + cr*128 + cs*64)*HH + hv*4];
        float4 vn = *(const float4*)(vp);
        #pragma unroll
        for (int i = 0; i < 64; ++i) {
            float4 vc = vn;
            if (i < 63) vn = *(const float4*)(vp + (i+1)*HH);
            float4 p4 = *(const float4*)&pT_w[wave][cs*64 + i][0];  // 2-addr broadcast
            acc[0].x=fmaf(p4.x,vc.x,acc[0].x); acc[0].y=fmaf(p4.x,vc.y,acc[0].y);
            acc[0].z=fmaf(p4.x,vc.z,acc[0].z); acc[0].w=fmaf(p4.x,vc.w,acc[0].w);
            acc[1].x=fmaf(p4.y,vc.x,acc[1].x); acc[1].y=fmaf(p4.y,vc.y,acc[1].y);
            acc[1].z=fmaf(p4.y,vc.z,acc[1].z); acc[1].w=fmaf(p4.y,vc.w,acc[1].w);
            acc[2].x=fmaf(p4.z,vc.x,acc[2].x); acc[2].y=fmaf(p4.z,vc.y,acc[2].y);
            acc[2].z=fmaf(p4.z,vc.z,acc[2].z); acc[2].w=fmaf(p4.z,vc.w,acc[2].w);
            acc[3].x=fmaf(p4.w,vc.x,acc[3].x); acc[3].y=fmaf(p4.w,vc.y,acc[3].y);
            acc[3].z=fmaf(p4.w,vc.z,acc[3].z); acc[3].w=fmaf(p4.w,vc.w,acc[3].w);
        }
        #pragma unroll
        for (int tt = 0; tt < 4; ++tt) {
            acc[tt].x += __shfl_xor(acc[tt].x, 32);
            acc[tt].y += __shfl_xor(acc[tt].y, 32);
            acc[tt].z += __shfl_xor(acc[tt].z, 32);
            acc[tt].w += __shfl_xor(acc[tt].w, 32);
        }
        if (cs == 0) {
            #pragma unroll
            for (int tt = 0; tt < 4; ++tt)
                *(float4*)&partial[wave][tt][hv*4] = acc[tt];
        }
    }
    __syncthreads();

    // ---- flash-merge 4 c-ranges per t-half -> rep ----
    #pragma unroll
    for (int e = tid; e < TT*HH; e += 512) {
        const int t = e >> 7, h = e & 127;
        const int thh = t >> 2, tl = t & 3;
        float2 q0 = wml[thh*4+0][tl], q1 = wml[thh*4+1][tl];
        float2 q2 = wml[thh*4+2][tl], q3 = wml[thh*4+3][tl];
        float M = fmaxf(fmaxf(q0.x,q1.x), fmaxf(q2.x,q3.x));
        float a0 = __expf(q0.x-M), a1 = __expf(q1.x-M);
        float a2 = __expf(q2.x-M), a3 = __expf(q3.x-M);
        float L = fmaf(a0,q0.y, fmaf(a1,q1.y, fmaf(a2,q2.y, a3*q3.y)));
        float r = a0*partial[thh*4+0][tl][h] + a1*partial[thh*4+1][tl][h]
                + a2*partial[thh*4+2][tl][h] + a3*partial[thh*4+3][tl][h];
        rep[t][h] = r / L;
    }
    __syncthreads();

    // ---- projection: thread (lt 0..3, h) -> rows lt and lt+4 ----
    {
        const int lt = tid >> 7, h = tid & 127;
        float o0 = b_tgt[h], o1 = o0;
        for (int k = 0; k < HH; k += 4) {
            float4 r0 = *(const float4*)&rep[lt    ][k];
            float4 r1 = *(const float4*)&rep[lt + 4][k];
            float w0 = W_tgt[(k+0)*HH + h];
            float w1 = W_tgt[(k+1)*HH + h];
            float w2 = W_tgt[(k+2)*HH + h];
            float w3 = W_tgt[(k+3)*HH + h];
            o0 = fmaf(r0.x,w0, fmaf(r0.y,w1, fmaf(r0.z,w2, fmaf(r0.w,w3, o0))));
            o1 = fmaf(r1.x,w0, fmaf(r1.y,w1, fmaf(r1.z,w2, fmaf(r1.w,w3, o1))));
        }
        out[(b*TDIM + t0 + lt    )*HH + h] = o0;
        out[(b*TDIM + t0 + lt + 4)*HH + h] = o1;
    }
}

extern "C" void kernel_launch(void* const* d_in, const int* in_sizes, int n_in,
                              void* d_out, int out_size, void* d_ws, size_t ws_size,
                              hipStream_t stream) {
    const float* ctx_x = (const float*)d_in[0];
    const float* ctx_y = (const float*)d_in[1];
    const float* tgt_x = (const float*)d_in[2];
    const float* W_in  = (const float*)d_in[3];
    const float* b_in  = (const float*)d_in[4];
    const float* W_ctx = (const float*)d_in[5];
    const float* b_ctx = (const float*)d_in[6];
    const float* W_tgt = (const float*)d_in[7];
    const float* b_tgt = (const float*)d_in[8];

    float* ws    = (float*)d_ws;
    float* key   = ws;                      // 262144 f32
    float* query = ws + 1*BB*CC*HH;         // 262144
    float* value = ws + 2*BB*CC*HH;         // 262144

    prep_kernel<<<BB*CC, 128, 0, stream>>>(ctx_x, ctx_y, tgt_x,
                                           W_in, b_in, W_ctx, b_ctx,
                                           key, query, value);
    fused_kernel<<<BB*(TDIM/TT), 512, 0, stream>>>(key, query, value,
                                                   W_tgt, b_tgt, (float*)d_out);
}